// Round 5
// baseline (256.672 us; speedup 1.0000x reference)
//
#include <hip/hip_runtime.h>
#include <math.h>

// B=4, L=1024, D=512, H=8, d=64
#define L_ 1024
#define D_ 512

typedef _Float16 half8 __attribute__((ext_vector_type(8)));
typedef _Float16 half4v __attribute__((ext_vector_type(4)));
typedef float floatx4 __attribute__((ext_vector_type(4)));
typedef float floatx2 __attribute__((ext_vector_type(2)));

// ---------- prep: K,Q -> fp16 straight; V -> fp16 transposed Vt[b][h][d][m]
__global__ __launch_bounds__(256) void prep(
    const float* __restrict__ K, const float* __restrict__ Q,
    const float* __restrict__ V,
    _Float16* __restrict__ K16, _Float16* __restrict__ Q16,
    _Float16* __restrict__ Vt)
{
    __shared__ _Float16 tile[64][72];
    const int t = threadIdx.x;
    const int bi = blockIdx.x;
    if (bi < 256) {
        for (int it = 0; it < 16; ++it) {
            size_t f = (size_t)bi * 4096 + it * 256 + t;
            const float4* src; _Float16* dst;
            if (f < 524288) { src = (const float4*)K; dst = K16; }
            else            { src = (const float4*)Q; dst = Q16; f -= 524288; }
            float4 v = src[f];
            half4v h = { (_Float16)v.x, (_Float16)v.y, (_Float16)v.z, (_Float16)v.w };
            *(half4v*)&dst[f * 4] = h;
        }
    } else {
        const int id = bi - 256;            // 512 blocks: 4b x 8h x 16 mtiles
        const int mt = id & 15, h = (id >> 4) & 7, b = id >> 7;
        const float4* Vf4 = (const float4*)V;
        for (int it = 0; it < 4; ++it) {
            const int ml = (t >> 4) + 16 * it;
            const int c4 = t & 15;
            float4 v = Vf4[(size_t)(b * 1024 + mt * 64 + ml) * 128 + h * 16 + c4];
            tile[c4 * 4 + 0][ml] = (_Float16)v.x;
            tile[c4 * 4 + 1][ml] = (_Float16)v.y;
            tile[c4 * 4 + 2][ml] = (_Float16)v.z;
            tile[c4 * 4 + 3][ml] = (_Float16)v.w;
        }
        __syncthreads();
        const int d = t >> 2, seg = t & 3;
        half8 o0 = *(half8*)&tile[d][seg * 16];
        half8 o1 = *(half8*)&tile[d][seg * 16 + 8];
        size_t obase = ((size_t)(b * 8 + h) * 64 + d) * 1024 + mt * 64 + seg * 16;
        *(half8*)&Vt[obase] = o0;
        *(half8*)&Vt[obase + 8] = o1;
    }
}

// ---------- fused: QK (transposed orient) -> LN(heads) -> exp -> PV, all in
// one block per (b, 16-l tile). e persisted fp8 in LDS for the w-colsum.
// LDS partition (dynamic, 134656 B):
//   [0,132096)      : e8[16l][1024m(^l)][8h] bytes  /  accf[4wv][16l][516] f32
//   [132096,134144) : rsum[4wv][16l][8h] f32
//   [134144,134656) : invs[16l][8h] f32
__global__ __launch_bounds__(256, 1) void fused(
    const _Float16* __restrict__ K16, const _Float16* __restrict__ Q16,
    const _Float16* __restrict__ Vt,  const float* __restrict__ doc,
    const float* __restrict__ gamma,  const float* __restrict__ beta,
    float* __restrict__ out, float* __restrict__ wacc)
{
    extern __shared__ unsigned char smem[];
    unsigned char* e8  = smem;
    float* accf = (float*)smem;
    float* rsum = (float*)(smem + 132096);
    float* invs = (float*)(smem + 134144);

    const int t = threadIdx.x, wv = t >> 6, lane = t & 63;
    const int c = lane & 15, q = lane >> 4;
    const int b = blockIdx.x & 3, lt = blockIdx.x >> 2;
    const int l0 = lt * 16;
    const int len = (int)doc[b];

    float g[8], be[8], M = 0.f;
    #pragma unroll
    for (int h = 0; h < 8; ++h) {
        g[h] = gamma[h]; be[h] = beta[h];
        M = fmaxf(M, 2.8285f * fabsf(g[h]) + fabsf(be[h]));
    }

    // K-frags (B-operand of QK), row l = l0 + c, persistent in regs
    const _Float16* Kb = K16 + (size_t)b * 524288 + (size_t)(l0 + c) * 512;
    half8 kf0[8], kf1[8];
    #pragma unroll
    for (int h = 0; h < 8; ++h) {
        kf0[h] = *(const half8*)&Kb[h * 64 + q * 8];
        kf1[h] = *(const half8*)&Kb[h * 64 + 32 + q * 8];
    }

    floatx4 acc[8][4];
    #pragma unroll
    for (int h = 0; h < 8; ++h)
        #pragma unroll
        for (int dt = 0; dt < 4; ++dt) acc[h][dt] = (floatx4){0.f, 0.f, 0.f, 0.f};
    float racc[8];
    #pragma unroll
    for (int h = 0; h < 8; ++h) racc[h] = 0.f;

    const _Float16* Qb = Q16 + (size_t)b * 524288;
    const _Float16* Vb = Vt + (size_t)b * 524288;
    const bool lok = (l0 + c) < len;
    const int mbase = wv * 256;

    for (int mt = 0; mt < 16; ++mt) {
        const int tb = mbase + mt * 16;
        const _Float16* Qr = Qb + (size_t)(tb + c) * 512;
        floatx4 cf[8];
        #pragma unroll
        for (int h = 0; h < 8; ++h) {
            half8 a0 = *(const half8*)&Qr[h * 64 + q * 8];
            half8 a1 = *(const half8*)&Qr[h * 64 + 32 + q * 8];
            floatx4 z = {0.f, 0.f, 0.f, 0.f};
            z     = __builtin_amdgcn_mfma_f32_16x16x32_f16(a0, kf0[h], z, 0, 0, 0);
            cf[h] = __builtin_amdgcn_mfma_f32_16x16x32_f16(a1, kf1[h], z, 0, 0, 0);
        }
        // LayerNorm over heads + exp(val - M); lane holds (l=l0+c, m=tb+q*4+r)
        #pragma unroll
        for (int r = 0; r < 4; ++r) {
            const int m = tb + q * 4 + r;
            const bool keep = lok && (m < len);
            float mu = 0.f;
            #pragma unroll
            for (int h = 0; h < 8; ++h) mu += cf[h][r];
            mu *= 0.125f;
            float var = 0.f;
            #pragma unroll
            for (int h = 0; h < 8; ++h) { float dd = cf[h][r] - mu; var += dd * dd; }
            var *= 0.125f;
            const float rs = 1.0f / sqrtf(var + 1e-5f);
            #pragma unroll
            for (int h = 0; h < 8; ++h) {
                float ev = 0.f;
                if (keep) {
                    float val = (cf[h][r] - mu) * rs * g[h] + be[h];
                    ev = __expf(val - M);
                }
                cf[h][r] = ev;
                racc[h] += ev;
            }
        }
        // persist e as fp8 in LDS: e8[(l=c)][m^c][h], 8B per (l,m)
        #pragma unroll
        for (int r = 0; r < 4; ++r) {
            const int m = tb + q * 4 + r;
            int lo = __builtin_amdgcn_cvt_pk_fp8_f32(cf[0][r], cf[1][r], 0, false);
            lo     = __builtin_amdgcn_cvt_pk_fp8_f32(cf[2][r], cf[3][r], lo, true);
            int hi = __builtin_amdgcn_cvt_pk_fp8_f32(cf[4][r], cf[5][r], 0, false);
            hi     = __builtin_amdgcn_cvt_pk_fp8_f32(cf[6][r], cf[7][r], hi, true);
            *(int2*)(e8 + ((size_t)(c * 1024 + (m ^ c)) * 8)) = make_int2(lo, hi);
        }
        // PV: QK C-frag == PV A-frag (16x16x16), just pack to fp16
        #pragma unroll
        for (int h = 0; h < 8; ++h) {
            half4v pa;
            #pragma unroll
            for (int j = 0; j < 4; ++j) pa[j] = (_Float16)cf[h][j];
            #pragma unroll
            for (int dt = 0; dt < 4; ++dt) {
                const _Float16* vr = Vb + (size_t)(h * 64 + dt * 16 + c) * 1024
                                        + tb + q * 4;
                half4v vb4 = *(const half4v*)vr;
                acc[h][dt] = __builtin_amdgcn_mfma_f32_16x16x16f16(
                    pa, vb4, acc[h][dt], 0, 0, 0);
            }
        }
    }

    // rowsums: reduce over q (m-subsets), then over waves via LDS
    #pragma unroll
    for (int h = 0; h < 8; ++h) {
        float s = racc[h];
        s += __shfl_xor(s, 16);
        s += __shfl_xor(s, 32);
        if (q == 0) rsum[wv * 128 + c * 8 + h] = s;
    }
    __syncthreads();
    if (t < 128) {
        const int ll = t >> 3;
        float s = rsum[t] + rsum[128 + t] + rsum[256 + t] + rsum[384 + t];
        invs[t] = ((l0 + ll) < len && s > 0.f) ? 1.0f / s : 0.f;
    }
    __syncthreads();

    // w pass: thread t owns m = t + 256u; w[m] += sum_{h,l} e*inv[l,h]
    {
        float wsum[4] = {0.f, 0.f, 0.f, 0.f};
        for (int l = 0; l < 16; ++l) {
            floatx4 iv0 = *(floatx4*)&invs[l * 8];
            floatx4 iv1 = *(floatx4*)&invs[l * 8 + 4];
            #pragma unroll
            for (int u = 0; u < 4; ++u) {
                const int m = t + 256 * u;
                int2 v = *(int2*)(e8 + ((size_t)(l * 1024 + (m ^ l)) * 8));
                floatx2 p01 = __builtin_amdgcn_cvt_pk_f32_fp8(v.x, false);
                floatx2 p23 = __builtin_amdgcn_cvt_pk_f32_fp8(v.x, true);
                floatx2 p45 = __builtin_amdgcn_cvt_pk_f32_fp8(v.y, false);
                floatx2 p67 = __builtin_amdgcn_cvt_pk_f32_fp8(v.y, true);
                wsum[u] += p01[0] * iv0[0] + p01[1] * iv0[1]
                         + p23[0] * iv0[2] + p23[1] * iv0[3]
                         + p45[0] * iv1[0] + p45[1] * iv1[1]
                         + p67[0] * iv1[2] + p67[1] * iv1[3];
            }
        }
        #pragma unroll
        for (int u = 0; u < 4; ++u)
            atomicAdd(&wacc[b * 1024 + t + 256 * u], wsum[u]);
    }
    __syncthreads();   // e8 reads done; region now reused as accf

    // cross-wave O' reduction via LDS
    #pragma unroll
    for (int h = 0; h < 8; ++h)
        #pragma unroll
        for (int dt = 0; dt < 4; ++dt)
            #pragma unroll
            for (int r = 0; r < 4; ++r)
                accf[(size_t)(wv * 16 + q * 4 + r) * 516 + h * 64 + dt * 16 + c]
                    = acc[h][dt][r];
    __syncthreads();

    // epilogue: out[b, l0+l, hd] = inv[l,h] * sum_wv accf
    {
        const int l = t >> 4, hd0 = (t & 15) * 32;
        const int h = hd0 >> 6;
        const float iv = invs[l * 8 + h];
        float* orow = out + (size_t)(b * 1024 + l0 + l) * 512 + hd0;
        #pragma unroll
        for (int j = 0; j < 8; ++j) {
            floatx4 s = {0.f, 0.f, 0.f, 0.f};
            #pragma unroll
            for (int w = 0; w < 4; ++w)
                s += *(floatx4*)&accf[(size_t)(w * 16 + l) * 516 + hd0 + j * 4];
            s *= iv;
            *(floatx4*)&orow[j * 4] = s;
        }
    }
}

// ---------- w finalize: w = softmax_m( (wacc/8)/len ), invalid -> 0
__global__ __launch_bounds__(256) void w_final(
    const float* __restrict__ wacc, const float* __restrict__ doc,
    float* __restrict__ wout)
{
    const int b = blockIdx.x;
    const int t = threadIdx.x;
    __shared__ float red[4];

    const float ds = doc[b];
    const int len = (int)ds;

    float v[4];
    float mx = -INFINITY;
    #pragma unroll
    for (int i = 0; i < 4; ++i) {
        const int m = t + 256 * i;
        const float raw = wacc[b * L_ + m];
        v[i] = (m < len) ? (raw * 0.125f) / ds : -INFINITY;
        mx = fmaxf(mx, v[i]);
    }
    #pragma unroll
    for (int off = 1; off < 64; off <<= 1) mx = fmaxf(mx, __shfl_xor(mx, off));
    if ((t & 63) == 0) red[t >> 6] = mx;
    __syncthreads();
    mx = fmaxf(fmaxf(red[0], red[1]), fmaxf(red[2], red[3]));

    float e[4];
    float sm = 0.f;
    #pragma unroll
    for (int i = 0; i < 4; ++i) {
        e[i] = (v[i] != -INFINITY) ? __expf(v[i] - mx) : 0.f;
        sm += e[i];
    }
    #pragma unroll
    for (int off = 1; off < 64; off <<= 1) sm += __shfl_xor(sm, off);
    __syncthreads();
    if ((t & 63) == 0) red[t >> 6] = sm;
    __syncthreads();
    sm = red[0] + red[1] + red[2] + red[3];
    const float inv = (sm > 0.f) ? 1.0f / sm : 0.f;

    #pragma unroll
    for (int i = 0; i < 4; ++i)
        wout[b * L_ + t + 256 * i] = e[i] * inv;
}

extern "C" void kernel_launch(void* const* d_in, const int* in_sizes, int n_in,
                              void* d_out, int out_size, void* d_ws, size_t ws_size,
                              hipStream_t stream)
{
    const float* K     = (const float*)d_in[0];
    const float* Q     = (const float*)d_in[1];
    const float* V     = (const float*)d_in[2];
    const float* doc   = (const float*)d_in[3];
    const float* gamma = (const float*)d_in[4];
    const float* beta  = (const float*)d_in[5];

    float* out  = (float*)d_out;
    float* wout = out + (size_t)4 * L_ * D_;

    _Float16* K16 = (_Float16*)d_ws;        // 4 MB
    _Float16* Q16 = K16 + 2097152;          // +4 MB
    _Float16* Vt  = Q16 + 2097152;          // +4 MB
    float*    wacc = (float*)(Vt + 2097152);

    (void)hipFuncSetAttribute((const void*)fused,
                              hipFuncAttributeMaxDynamicSharedMemorySize, 134656);

    (void)hipMemsetAsync(wacc, 0, 4096 * sizeof(float), stream);
    prep   <<<dim3(768), dim3(256), 0,      stream>>>(K, Q, V, K16, Q16, Vt);
    fused  <<<dim3(256), dim3(256), 134656, stream>>>(K16, Q16, Vt, doc, gamma,
                                                      beta, out, wacc);
    w_final<<<dim3(4),   dim3(256), 0,      stream>>>(wacc, doc, wout);
}